// Round 1
// baseline (1924.803 us; speedup 1.0000x reference)
//
#include <hip/hip_runtime.h>
#include <hip/hip_bf16.h>
#include <math.h>

#define NNODES 50000
#define NEDGES 500000
#define DIM 128
#define NREL 51
#define NLAYERS 4
#define NTRIPLES (1024*32)
#define KDIM 1664   // 13*128

typedef float f2 __attribute__((ext_vector_type(2)));

static __device__ __forceinline__ f2 fmax2(f2 a, f2 b) { f2 r; r.x = fmaxf(a.x,b.x); r.y = fmaxf(a.y,b.y); return r; }
static __device__ __forceinline__ f2 fmin2(f2 a, f2 b) { f2 r; r.x = fminf(a.x,b.x); r.y = fminf(a.y,b.y); return r; }

// ---------------- graph prep ----------------

__global__ void deg_hist_k(const int* __restrict__ ei, int* __restrict__ deg) {
  int e = blockIdx.x * blockDim.x + threadIdx.x;
  if (e < NEDGES) atomicAdd(&deg[ei[NEDGES + e]], 1);
}

__global__ void logsum_k(const int* __restrict__ deg, float* __restrict__ acc) {
  int i = blockIdx.x * blockDim.x + threadIdx.x;
  float v = (i < NNODES) ? logf((float)(deg[i] + 1)) : 0.0f;
  #pragma unroll
  for (int m = 32; m >= 1; m >>= 1) v += __shfl_xor(v, m, 64);
  __shared__ float ws[4];
  int lane = threadIdx.x & 63, w = threadIdx.x >> 6;
  if (lane == 0) ws[w] = v;
  __syncthreads();
  if (threadIdx.x == 0) atomicAdd(acc, ws[0] + ws[1] + ws[2] + ws[3]);
}

__global__ void scan_deg_k(const int* __restrict__ deg, int* __restrict__ row_start,
                           int* __restrict__ cursor) {
  __shared__ int sm[1024];
  __shared__ int carry_s;
  int t = threadIdx.x;
  if (t == 0) carry_s = 0;
  __syncthreads();
  for (int base = 0; base < NNODES; base += 1024) {
    int idx = base + t;
    int v = (idx < NNODES) ? deg[idx] : 0;
    sm[t] = v;
    __syncthreads();
    for (int off = 1; off < 1024; off <<= 1) {
      int add = (t >= off) ? sm[t - off] : 0;
      __syncthreads();
      sm[t] += add;
      __syncthreads();
    }
    int excl = carry_s + sm[t] - v;
    if (idx < NNODES) { row_start[idx] = excl; cursor[idx] = excl; }
    __syncthreads();
    if (t == 0) carry_s += sm[1023];
    __syncthreads();
  }
  if (t == 0) row_start[NNODES] = carry_s;
}

__global__ void scales_k(const int* __restrict__ deg, const float* __restrict__ logsum,
                         float* __restrict__ scales) {
  int i = blockIdx.x * blockDim.x + threadIdx.x;
  if (i >= NNODES) return;
  float mean = *logsum / (float)NNODES;
  float sc = logf((float)(deg[i] + 1)) / mean;
  scales[i*3 + 0] = 1.0f;
  scales[i*3 + 1] = sc;
  scales[i*3 + 2] = 1.0f / fmaxf(sc, 0.01f);
}

__global__ void scatter_k(const int* __restrict__ ei, const int* __restrict__ etype,
                          const float* __restrict__ ew, int* __restrict__ cursor,
                          int* __restrict__ s_srt, int* __restrict__ t_srt,
                          float* __restrict__ w_srt) {
  int e = blockIdx.x * blockDim.x + threadIdx.x;
  if (e >= NEDGES) return;
  int d = ei[NEDGES + e];
  int pos = atomicAdd(&cursor[d], 1);
  s_srt[pos] = ei[e];
  t_srt[pos] = etype[e];
  w_srt[pos] = ew[e];
}

// ---------------- per-layer aggregation (one wave per destination node) ----------------

__global__ __launch_bounds__(256) void aggregate_k(
    const float* __restrict__ x, const float* __restrict__ x0,
    const float* __restrict__ relw, const int* __restrict__ row_start,
    const int* __restrict__ s_srt, const int* __restrict__ t_srt,
    const float* __restrict__ w_srt, float* __restrict__ stats)
{
  int wid = blockIdx.x * 4 + (threadIdx.x >> 6);
  if (wid >= NNODES) return;
  int lane = threadIdx.x & 63;
  int j0 = lane * 2;
  int beg = row_start[wid], end = row_start[wid + 1];
  f2 sum = {0.f, 0.f}, sq = {0.f, 0.f};
  f2 mx = {-INFINITY, -INFINITY}, mn = {INFINITY, INFINITY};
  for (int e = beg; e < end; ++e) {
    int s = s_srt[e]; int ty = t_srt[e]; float w = w_srt[e];
    f2 xs = *(const f2*)(x + (size_t)s * DIM + j0);
    f2 rv = *(const f2*)(relw + (size_t)ty * DIM + j0);
    f2 m = xs * rv * w;
    sum += m; sq += m * m;
    mx = fmax2(mx, m); mn = fmin2(mn, m);
  }
  f2 x0v = *(const f2*)(x0 + (size_t)wid * DIM + j0);
  sum += x0v; sq += x0v * x0v;
  mx = fmax2(mx, x0v); mn = fmin2(mn, x0v);
  float dq = (float)(end - beg + 1);
  f2 mean = sum / dq;
  f2 sqm = sq / dq;
  f2 var = sqm - mean * mean;
  f2 sd; sd.x = sqrtf(fmaxf(var.x, 1e-6f)); sd.y = sqrtf(fmaxf(var.y, 1e-6f));
  float* sp = stats + (size_t)wid * 512;
  *(f2*)(sp + 0*DIM + j0) = mean;
  *(f2*)(sp + 1*DIM + j0) = mx;
  *(f2*)(sp + 2*DIM + j0) = mn;
  *(f2*)(sp + 3*DIM + j0) = sd;
}

// ---------------- fused GEMM (A expanded on the fly) + bias + LN + relu + residual ----------------
// A[n,c] = c<1536 ? stats[n, (c/128)%4, c%128] * scales[n, c/512] : x[n, c-1536]
// out = A @ W + b ; LN ; relu ; x += out   (in place on x)

__global__ __launch_bounds__(256) void gemm_ln_k(
    const float* __restrict__ stats, const float* __restrict__ scales,
    float* __restrict__ x,
    const float* __restrict__ W, const float* __restrict__ bias,
    const float* __restrict__ gam, const float* __restrict__ bet)
{
  __shared__ float As[64][32];
  __shared__ float Ws[32][128];
  int row0 = blockIdx.x * 64;
  int t = threadIdx.x;
  int col0 = (t & 31) * 4;
  int rg = t >> 5;      // 0..7 row-group
  int r0 = rg * 8;
  f2 acc[8][2];
  #pragma unroll
  for (int i = 0; i < 8; i++) { acc[i][0] = (f2){0.f,0.f}; acc[i][1] = (f2){0.f,0.f}; }

  for (int k0 = 0; k0 < KDIM; k0 += 32) {
    __syncthreads();
    // stage W tile (32 x 128)
    const float4* Wg = (const float4*)(W + (size_t)k0 * 128);
    float4* WsV = (float4*)&Ws[0][0];
    #pragma unroll
    for (int i = 0; i < 4; i++) WsV[i*256 + t] = Wg[i*256 + t];
    // stage A tile (64 x 32) with on-the-fly PNA expansion
    if (k0 < 1536) {
      int s = k0 / 512;
      int f = (k0 >> 7) & 3;
      int dbase = k0 & 127;
      #pragma unroll
      for (int i = 0; i < 8; i++) {
        int flat = i*256 + t;
        int r = flat >> 5, kk = flat & 31;
        int n = row0 + r; if (n > NNODES - 1) n = NNODES - 1;
        As[r][kk] = stats[(size_t)n*512 + f*128 + dbase + kk] * scales[n*3 + s];
      }
    } else {
      int dbase = k0 - 1536;
      #pragma unroll
      for (int i = 0; i < 8; i++) {
        int flat = i*256 + t;
        int r = flat >> 5, kk = flat & 31;
        int n = row0 + r; if (n > NNODES - 1) n = NNODES - 1;
        As[r][kk] = x[(size_t)n*DIM + dbase + kk];
      }
    }
    __syncthreads();
    #pragma unroll
    for (int kk = 0; kk < 32; ++kk) {
      f2 w01 = *(const f2*)&Ws[kk][col0];
      f2 w23 = *(const f2*)&Ws[kk][col0 + 2];
      #pragma unroll
      for (int i = 0; i < 8; i++) {
        float a = As[r0 + i][kk];
        acc[i][0] += w01 * a;
        acc[i][1] += w23 * a;
      }
    }
  }

  // epilogue: bias + layernorm + relu + residual, stored in place
  f2 bi01; bi01.x = bias[col0]; bi01.y = bias[col0+1];
  f2 bi23; bi23.x = bias[col0+2]; bi23.y = bias[col0+3];
  f2 g01;  g01.x = gam[col0];  g01.y = gam[col0+1];
  f2 g23;  g23.x = gam[col0+2]; g23.y = gam[col0+3];
  f2 be01; be01.x = bet[col0]; be01.y = bet[col0+1];
  f2 be23; be23.x = bet[col0+2]; be23.y = bet[col0+3];
  #pragma unroll
  for (int i = 0; i < 8; i++) {
    acc[i][0] += bi01; acc[i][1] += bi23;
    float s = acc[i][0].x + acc[i][0].y + acc[i][1].x + acc[i][1].y;
    float q = acc[i][0].x*acc[i][0].x + acc[i][0].y*acc[i][0].y
            + acc[i][1].x*acc[i][1].x + acc[i][1].y*acc[i][1].y;
    #pragma unroll
    for (int m = 1; m < 32; m <<= 1) { s += __shfl_xor(s, m, 64); q += __shfl_xor(q, m, 64); }
    float mu = s * (1.0f/128.0f);
    float var = q * (1.0f/128.0f) - mu*mu;
    float rstd = rsqrtf(var + 1e-5f);
    int n = row0 + r0 + i;
    if (n < NNODES) {
      f2 o01 = (acc[i][0] - mu) * rstd * g01 + be01;
      f2 o23 = (acc[i][1] - mu) * rstd * g23 + be23;
      o01.x = fmaxf(o01.x, 0.f); o01.y = fmaxf(o01.y, 0.f);
      o23.x = fmaxf(o23.x, 0.f); o23.y = fmaxf(o23.y, 0.f);
      float4 xr = *(const float4*)(x + (size_t)n*DIM + col0);
      float4 res; res.x = o01.x + xr.x; res.y = o01.y + xr.y;
                  res.z = o23.x + xr.z; res.w = o23.y + xr.w;
      *(float4*)(x + (size_t)n*DIM + col0) = res;
    }
  }
}

// ---------------- distmult scoring ----------------

__global__ __launch_bounds__(256) void score_k(
    const float* __restrict__ x, const float* __restrict__ qw,
    const int* __restrict__ src, const int* __restrict__ rel,
    const int* __restrict__ dst, float* __restrict__ out)
{
  int wid = blockIdx.x * 4 + (threadIdx.x >> 6);
  if (wid >= NTRIPLES) return;
  int lane = threadIdx.x & 63;
  int j0 = lane * 2;
  int s = src[wid], r = rel[wid], d = dst[wid];
  f2 xs = *(const f2*)(x  + (size_t)s*DIM + j0);
  f2 q  = *(const f2*)(qw + (size_t)r*DIM + j0);
  f2 xd = *(const f2*)(x  + (size_t)d*DIM + j0);
  float p = xs.x*q.x*xd.x + xs.y*q.y*xd.y;
  #pragma unroll
  for (int m = 32; m >= 1; m >>= 1) p += __shfl_xor(p, m, 64);
  if (lane == 0) out[wid] = p;
}

// ---------------- launch ----------------

extern "C" void kernel_launch(void* const* d_in, const int* in_sizes, int n_in,
                              void* d_out, int out_size, void* d_ws, size_t ws_size,
                              hipStream_t stream) {
  const float* x0    = (const float*)d_in[0];
  const int*   ei    = (const int*)d_in[1];
  const int*   etyp  = (const int*)d_in[2];
  const float* ew    = (const float*)d_in[3];
  const float* rel_w = (const float*)d_in[4];
  const float* lin_w = (const float*)d_in[5];
  const float* lin_b = (const float*)d_in[6];
  const float* ln_g  = (const float*)d_in[7];
  const float* ln_b  = (const float*)d_in[8];
  const float* qw    = (const float*)d_in[9];
  const int*   srcq  = (const int*)d_in[10];
  const int*   relq  = (const int*)d_in[11];
  const int*   dstq  = (const int*)d_in[12];
  float* out = (float*)d_out;

  char* ws = (char*)d_ws;
  size_t off = 0;
  auto alloc = [&](size_t bytes) -> void* {
    void* p = ws + off; off = (off + bytes + 255) & ~(size_t)255; return p;
  };
  int*   deg       = (int*)alloc((size_t)NNODES * 4);
  int*   row_start = (int*)alloc((size_t)(NNODES + 1) * 4);
  int*   cursor    = (int*)alloc((size_t)NNODES * 4);
  int*   s_srt     = (int*)alloc((size_t)NEDGES * 4);
  int*   t_srt     = (int*)alloc((size_t)NEDGES * 4);
  float* w_srt     = (float*)alloc((size_t)NEDGES * 4);
  float* scales    = (float*)alloc((size_t)NNODES * 3 * 4);
  float* logsum    = (float*)alloc(256);
  float* stats     = (float*)alloc((size_t)NNODES * 512 * 4);
  float* xbuf      = (float*)alloc((size_t)NNODES * DIM * 4);

  hipMemsetAsync(deg, 0, (size_t)NNODES * 4, stream);
  hipMemsetAsync(logsum, 0, 4, stream);
  deg_hist_k<<<(NEDGES + 255) / 256, 256, 0, stream>>>(ei, deg);
  logsum_k<<<(NNODES + 255) / 256, 256, 0, stream>>>(deg, logsum);
  scan_deg_k<<<1, 1024, 0, stream>>>(deg, row_start, cursor);
  scales_k<<<(NNODES + 255) / 256, 256, 0, stream>>>(deg, logsum, scales);
  scatter_k<<<(NEDGES + 255) / 256, 256, 0, stream>>>(ei, etyp, ew, cursor, s_srt, t_srt, w_srt);
  hipMemcpyAsync(xbuf, x0, (size_t)NNODES * DIM * 4, hipMemcpyDeviceToDevice, stream);

  for (int l = 0; l < NLAYERS; ++l) {
    aggregate_k<<<(NNODES + 3) / 4, 256, 0, stream>>>(
        xbuf, x0, rel_w + (size_t)l * NREL * DIM, row_start, s_srt, t_srt, w_srt, stats);
    gemm_ln_k<<<(NNODES + 63) / 64, 256, 0, stream>>>(
        stats, scales, xbuf, lin_w + (size_t)l * KDIM * DIM,
        lin_b + (size_t)l * DIM, ln_g + (size_t)l * DIM, ln_b + (size_t)l * DIM);
  }
  score_k<<<(NTRIPLES + 3) / 4, 256, 0, stream>>>(xbuf, qw, srcq, relq, dstq, out);
}

// Round 2
// 878.715 us; speedup vs baseline: 2.1905x; 2.1905x over previous
//
#include <hip/hip_runtime.h>
#include <math.h>

#define NNODES 50000
#define NEDGES 500000
#define DIM 128
#define NREL 51
#define NLAYERS 4
#define NTRIPLES (1024*32)
#define KDIM 1664     // 13*128
#define NCHUNK 52     // KDIM/32
#define APAD 40       // padded LDS row length (bf16 elems): 80B stride -> conflict-free b128

typedef float f2 __attribute__((ext_vector_type(2)));
typedef float f32x4 __attribute__((ext_vector_type(4)));
typedef short bf16x8 __attribute__((ext_vector_type(8)));

static __device__ __forceinline__ ushort bf16_rne(float v) {
  unsigned u = __float_as_uint(v);
  unsigned r = (u + 0x7fffu + ((u >> 16) & 1u)) >> 16;
  return (ushort)r;
}
static __device__ __forceinline__ float bf16_f(ushort h) {
  return __uint_as_float(((unsigned)h) << 16);
}
static __device__ __forceinline__ f2 fmax2(f2 a, f2 b) { f2 r; r.x = fmaxf(a.x,b.x); r.y = fmaxf(a.y,b.y); return r; }
static __device__ __forceinline__ f2 fmin2(f2 a, f2 b) { f2 r; r.x = fminf(a.x,b.x); r.y = fminf(a.y,b.y); return r; }

// ---------------- graph prep ----------------

__global__ void deg_hist_k(const int* __restrict__ ei, int* __restrict__ deg) {
  int e = blockIdx.x * blockDim.x + threadIdx.x;
  if (e < NEDGES) atomicAdd(&deg[ei[NEDGES + e]], 1);
}

__global__ void logsum_k(const int* __restrict__ deg, float* __restrict__ acc) {
  int i = blockIdx.x * blockDim.x + threadIdx.x;
  float v = (i < NNODES) ? logf((float)(deg[i] + 1)) : 0.0f;
  #pragma unroll
  for (int m = 32; m >= 1; m >>= 1) v += __shfl_xor(v, m, 64);
  __shared__ float ws[4];
  int lane = threadIdx.x & 63, w = threadIdx.x >> 6;
  if (lane == 0) ws[w] = v;
  __syncthreads();
  if (threadIdx.x == 0) atomicAdd(acc, ws[0] + ws[1] + ws[2] + ws[3]);
}

__global__ void scan_deg_k(const int* __restrict__ deg, int* __restrict__ row_start,
                           int* __restrict__ cursor) {
  __shared__ int sm[1024];
  __shared__ int carry_s;
  int t = threadIdx.x;
  if (t == 0) carry_s = 0;
  __syncthreads();
  for (int base = 0; base < NNODES; base += 1024) {
    int idx = base + t;
    int v = (idx < NNODES) ? deg[idx] : 0;
    sm[t] = v;
    __syncthreads();
    for (int off = 1; off < 1024; off <<= 1) {
      int add = (t >= off) ? sm[t - off] : 0;
      __syncthreads();
      sm[t] += add;
      __syncthreads();
    }
    int excl = carry_s + sm[t] - v;
    if (idx < NNODES) { row_start[idx] = excl; cursor[idx] = excl; }
    __syncthreads();
    if (t == 0) carry_s += sm[1023];
    __syncthreads();
  }
  if (t == 0) row_start[NNODES] = carry_s;
}

__global__ void scales_k(const int* __restrict__ deg, const float* __restrict__ logsum,
                         float* __restrict__ scales) {
  int i = blockIdx.x * blockDim.x + threadIdx.x;
  if (i >= NNODES) return;
  float mean = *logsum / (float)NNODES;
  float sc = logf((float)(deg[i] + 1)) / mean;
  scales[i*3 + 0] = 1.0f;
  scales[i*3 + 1] = sc;
  scales[i*3 + 2] = 1.0f / fmaxf(sc, 0.01f);
}

__global__ void scatter_k(const int* __restrict__ ei, const int* __restrict__ etype,
                          const float* __restrict__ ew, int* __restrict__ cursor,
                          int* __restrict__ s_srt, int* __restrict__ t_srt,
                          float* __restrict__ w_srt) {
  int e = blockIdx.x * blockDim.x + threadIdx.x;
  if (e >= NEDGES) return;
  int d = ei[NEDGES + e];
  int pos = atomicAdd(&cursor[d], 1);
  s_srt[pos] = ei[e];
  t_srt[pos] = etype[e];
  w_srt[pos] = ew[e];
}

// ---------------- W pre-split: [l][c][{hi,lo}][col][APAD] bf16 ----------------

__global__ void wsplit_k(const float* __restrict__ W, ushort* __restrict__ wt) {
  int id = blockIdx.x * blockDim.x + threadIdx.x;
  if (id >= NLAYERS * KDIM * DIM) return;
  int col = id & 127;
  int k = (id >> 7) % KDIM;
  int l = id / (KDIM * DIM);
  float v = W[(size_t)l * KDIM * DIM + (size_t)k * DIM + col];
  ushort h = bf16_rne(v);
  ushort lo = bf16_rne(v - bf16_f(h));
  int c = k >> 5, kk = k & 31;
  size_t base = ((size_t)l * NCHUNK + c) * (2 * 128 * APAD);
  wt[base + 0 * 128 * APAD + col * APAD + kk] = h;
  wt[base + 1 * 128 * APAD + col * APAD + kk] = lo;
}

// ---------------- per-layer aggregation (one wave per destination node) ----------------

__global__ __launch_bounds__(256) void aggregate_k(
    const float* __restrict__ x, const float* __restrict__ x0,
    const float* __restrict__ relw, const int* __restrict__ row_start,
    const int* __restrict__ s_srt, const int* __restrict__ t_srt,
    const float* __restrict__ w_srt, float* __restrict__ stats)
{
  int wid = blockIdx.x * 4 + (threadIdx.x >> 6);
  if (wid >= NNODES) return;
  int lane = threadIdx.x & 63;
  int j0 = lane * 2;
  int beg = row_start[wid], end = row_start[wid + 1];
  f2 sum = {0.f, 0.f}, sq = {0.f, 0.f};
  f2 mx = {-INFINITY, -INFINITY}, mn = {INFINITY, INFINITY};
  for (int e = beg; e < end; ++e) {
    int s = s_srt[e]; int ty = t_srt[e]; float w = w_srt[e];
    f2 xs = *(const f2*)(x + (size_t)s * DIM + j0);
    f2 rv = *(const f2*)(relw + (size_t)ty * DIM + j0);
    f2 m = xs * rv * w;
    sum += m; sq += m * m;
    mx = fmax2(mx, m); mn = fmin2(mn, m);
  }
  f2 x0v = *(const f2*)(x0 + (size_t)wid * DIM + j0);
  sum += x0v; sq += x0v * x0v;
  mx = fmax2(mx, x0v); mn = fmin2(mn, x0v);
  float dq = (float)(end - beg + 1);
  f2 mean = sum / dq;
  f2 sqm = sq / dq;
  f2 var = sqm - mean * mean;
  f2 sd; sd.x = sqrtf(fmaxf(var.x, 1e-6f)); sd.y = sqrtf(fmaxf(var.y, 1e-6f));
  float* sp = stats + (size_t)wid * 512;
  *(f2*)(sp + 0*DIM + j0) = mean;
  *(f2*)(sp + 1*DIM + j0) = mx;
  *(f2*)(sp + 2*DIM + j0) = mn;
  *(f2*)(sp + 3*DIM + j0) = sd;
}

// ---------------- split-bf16 MFMA GEMM: Y = A_expanded @ W ----------------
// A[n,c] = c<1536 ? stats[n, (c/128)%4, c%128] * scales[n, c/512] : x[n, c-1536]
// 128x128 tile / block, 8 waves (2 row-strips x 4 col-strips), BK=32.
// a = a_hi + a_lo (bf16 split); acc += ah*bh + ah*bl + al*bh.

__global__ __launch_bounds__(512) void gemm_mfma_k(
    const float* __restrict__ stats, const float* __restrict__ scales,
    const float* __restrict__ x, const ushort* __restrict__ wt,
    float* __restrict__ Y)
{
  __shared__ ushort At[2 * 128 * APAD];   // hi then lo, [128][APAD] each
  __shared__ ushort Bt[2 * 128 * APAD];   // hi then lo, [col][APAD] each
  int t = threadIdx.x;
  int w = t >> 6, lane = t & 63;
  int lr = lane & 15, lk = lane >> 4;
  int wr = w >> 2, wc = w & 3;
  int row0 = blockIdx.x * 128;

  // staging role: A row sr, elems sq*8 .. sq*8+7
  int sr = t >> 2, sq = t & 3;
  int an = row0 + sr; if (an >= NNODES) an = NNODES - 1;
  float sc1 = scales[an*3 + 1];
  float sc2 = scales[an*3 + 2];

  f32x4 acc[4][2];
  #pragma unroll
  for (int i = 0; i < 4; ++i) {
    acc[i][0] = (f32x4){0.f,0.f,0.f,0.f};
    acc[i][1] = (f32x4){0.f,0.f,0.f,0.f};
  }

  for (int c = 0; c < NCHUNK; ++c) {
    int k0 = c * 32;
    // ---- global loads issued early (overlap prev MFMA) ----
    const float4* bsrc = (const float4*)(wt + (size_t)c * (2 * 128 * APAD));
    float4 b0 = bsrc[t];
    float4 b1 = bsrc[t + 512];
    float4 b2 = {0.f,0.f,0.f,0.f};
    if (t < 256) b2 = bsrc[t + 1024];
    float av[8];
    {
      const float* ap;
      float sc;
      if (k0 < 1536) {
        int s = k0 >> 9;
        int f = (k0 >> 7) & 3;
        int dbase = (k0 & 127) + sq * 8;
        ap = stats + (size_t)an * 512 + f * 128 + dbase;
        sc = (s == 0) ? 1.0f : ((s == 1) ? sc1 : sc2);
      } else {
        ap = x + (size_t)an * DIM + (k0 - 1536) + sq * 8;
        sc = 1.0f;
      }
      float4 a0 = *(const float4*)(ap);
      float4 a1 = *(const float4*)(ap + 4);
      av[0]=a0.x*sc; av[1]=a0.y*sc; av[2]=a0.z*sc; av[3]=a0.w*sc;
      av[4]=a1.x*sc; av[5]=a1.y*sc; av[6]=a1.z*sc; av[7]=a1.w*sc;
    }
    __syncthreads();   // previous iteration's frag reads complete
    // ---- split + LDS writes ----
    bf16x8 hv, lv;
    #pragma unroll
    for (int j = 0; j < 8; ++j) {
      ushort h = bf16_rne(av[j]);
      hv[j] = (short)h;
      lv[j] = (short)bf16_rne(av[j] - bf16_f(h));
    }
    {
      ushort* ad = At + sr * APAD + sq * 8;
      *(bf16x8*)ad = hv;
      *(bf16x8*)(ad + 128 * APAD) = lv;
      float4* bd = (float4*)Bt;
      bd[t] = b0;
      bd[t + 512] = b1;
      if (t < 256) bd[t + 1024] = b2;
    }
    __syncthreads();
    // ---- fragment loads + MFMA ----
    bf16x8 ah[4], al[4], bh[2], bl[2];
    const ushort* Ab = At + (wr * 64 + lr) * APAD + lk * 8;
    #pragma unroll
    for (int fr = 0; fr < 4; ++fr) {
      ah[fr] = *(const bf16x8*)(Ab + fr * 16 * APAD);
      al[fr] = *(const bf16x8*)(Ab + fr * 16 * APAD + 128 * APAD);
    }
    const ushort* Bb = Bt + (wc * 32 + lr) * APAD + lk * 8;
    #pragma unroll
    for (int fc = 0; fc < 2; ++fc) {
      bh[fc] = *(const bf16x8*)(Bb + fc * 16 * APAD);
      bl[fc] = *(const bf16x8*)(Bb + fc * 16 * APAD + 128 * APAD);
    }
    #pragma unroll
    for (int fr = 0; fr < 4; ++fr) {
      #pragma unroll
      for (int fc = 0; fc < 2; ++fc) {
        acc[fr][fc] = __builtin_amdgcn_mfma_f32_16x16x32_bf16(ah[fr], bh[fc], acc[fr][fc], 0, 0, 0);
        acc[fr][fc] = __builtin_amdgcn_mfma_f32_16x16x32_bf16(ah[fr], bl[fc], acc[fr][fc], 0, 0, 0);
        acc[fr][fc] = __builtin_amdgcn_mfma_f32_16x16x32_bf16(al[fr], bh[fc], acc[fr][fc], 0, 0, 0);
      }
    }
  }
  // ---- epilogue: raw GEMM result to Y (C/D: col=lane&15, row=(lane>>4)*4+reg) ----
  #pragma unroll
  for (int fr = 0; fr < 4; ++fr) {
    #pragma unroll
    for (int q = 0; q < 4; ++q) {
      int grow = row0 + wr * 64 + fr * 16 + lk * 4 + q;
      if (grow < NNODES) {
        #pragma unroll
        for (int fc = 0; fc < 2; ++fc)
          Y[(size_t)grow * DIM + wc * 32 + fc * 16 + lr] = acc[fr][fc][q];
      }
    }
  }
}

// ---------------- bias + LN + relu + residual (x updated in place) ----------------

__global__ __launch_bounds__(256) void ln_k(
    const float* __restrict__ Y, const float* __restrict__ bias,
    const float* __restrict__ gam, const float* __restrict__ bet,
    float* __restrict__ x)
{
  int wid = blockIdx.x * 4 + (threadIdx.x >> 6);
  if (wid >= NNODES) return;
  int lane = threadIdx.x & 63;
  int j0 = lane * 2;
  f2 v = *(const f2*)(Y + (size_t)wid * DIM + j0);
  f2 b = *(const f2*)(bias + j0);
  v += b;
  float s = v.x + v.y;
  float q = v.x * v.x + v.y * v.y;
  #pragma unroll
  for (int m = 1; m < 64; m <<= 1) { s += __shfl_xor(s, m, 64); q += __shfl_xor(q, m, 64); }
  float mu = s * (1.0f / 128.0f);
  float var = q * (1.0f / 128.0f) - mu * mu;
  float rstd = rsqrtf(var + 1e-5f);
  f2 g = *(const f2*)(gam + j0);
  f2 be = *(const f2*)(bet + j0);
  f2 o = (v - mu) * rstd * g + be;
  o.x = fmaxf(o.x, 0.f); o.y = fmaxf(o.y, 0.f);
  float* xp = x + (size_t)wid * DIM + j0;
  f2 xr = *(const f2*)xp;
  *(f2*)xp = o + xr;
}

// ---------------- distmult scoring ----------------

__global__ __launch_bounds__(256) void score_k(
    const float* __restrict__ x, const float* __restrict__ qw,
    const int* __restrict__ src, const int* __restrict__ rel,
    const int* __restrict__ dst, float* __restrict__ out)
{
  int wid = blockIdx.x * 4 + (threadIdx.x >> 6);
  if (wid >= NTRIPLES) return;
  int lane = threadIdx.x & 63;
  int j0 = lane * 2;
  int s = src[wid], r = rel[wid], d = dst[wid];
  f2 xs = *(const f2*)(x  + (size_t)s * DIM + j0);
  f2 q  = *(const f2*)(qw + (size_t)r * DIM + j0);
  f2 xd = *(const f2*)(x  + (size_t)d * DIM + j0);
  float p = xs.x*q.x*xd.x + xs.y*q.y*xd.y;
  #pragma unroll
  for (int m = 32; m >= 1; m >>= 1) p += __shfl_xor(p, m, 64);
  if (lane == 0) out[wid] = p;
}

// ---------------- launch ----------------

extern "C" void kernel_launch(void* const* d_in, const int* in_sizes, int n_in,
                              void* d_out, int out_size, void* d_ws, size_t ws_size,
                              hipStream_t stream) {
  const float* x0    = (const float*)d_in[0];
  const int*   ei    = (const int*)d_in[1];
  const int*   etyp  = (const int*)d_in[2];
  const float* ew    = (const float*)d_in[3];
  const float* rel_w = (const float*)d_in[4];
  const float* lin_w = (const float*)d_in[5];
  const float* lin_b = (const float*)d_in[6];
  const float* ln_g  = (const float*)d_in[7];
  const float* lnb   = (const float*)d_in[8];
  const float* qw    = (const float*)d_in[9];
  const int*   srcq  = (const int*)d_in[10];
  const int*   relq  = (const int*)d_in[11];
  const int*   dstq  = (const int*)d_in[12];
  float* out = (float*)d_out;

  char* ws = (char*)d_ws;
  size_t off = 0;
  auto alloc = [&](size_t bytes) -> void* {
    void* p = ws + off; off = (off + bytes + 255) & ~(size_t)255; return p;
  };
  int*    deg       = (int*)alloc((size_t)NNODES * 4);
  int*    row_start = (int*)alloc((size_t)(NNODES + 1) * 4);
  int*    cursor    = (int*)alloc((size_t)NNODES * 4);
  int*    s_srt     = (int*)alloc((size_t)NEDGES * 4);
  int*    t_srt     = (int*)alloc((size_t)NEDGES * 4);
  float*  w_srt     = (float*)alloc((size_t)NEDGES * 4);
  float*  scales    = (float*)alloc((size_t)NNODES * 3 * 4);
  float*  logsum    = (float*)alloc(256);
  float*  stats     = (float*)alloc((size_t)NNODES * 512 * 4);
  float*  xbuf      = (float*)alloc((size_t)NNODES * DIM * 4);
  float*  Ybuf      = (float*)alloc((size_t)NNODES * DIM * 4);
  ushort* wtbuf     = (ushort*)alloc((size_t)NLAYERS * NCHUNK * 2 * 128 * APAD * 2);

  hipMemsetAsync(deg, 0, (size_t)NNODES * 4, stream);
  hipMemsetAsync(logsum, 0, 4, stream);
  deg_hist_k<<<(NEDGES + 255) / 256, 256, 0, stream>>>(ei, deg);
  logsum_k<<<(NNODES + 255) / 256, 256, 0, stream>>>(deg, logsum);
  scan_deg_k<<<1, 1024, 0, stream>>>(deg, row_start, cursor);
  scales_k<<<(NNODES + 255) / 256, 256, 0, stream>>>(deg, logsum, scales);
  scatter_k<<<(NEDGES + 255) / 256, 256, 0, stream>>>(ei, etyp, ew, cursor, s_srt, t_srt, w_srt);
  wsplit_k<<<(NLAYERS * KDIM * DIM + 255) / 256, 256, 0, stream>>>(lin_w, wtbuf);
  hipMemcpyAsync(xbuf, x0, (size_t)NNODES * DIM * 4, hipMemcpyDeviceToDevice, stream);

  for (int l = 0; l < NLAYERS; ++l) {
    aggregate_k<<<(NNODES + 3) / 4, 256, 0, stream>>>(
        xbuf, x0, rel_w + (size_t)l * NREL * DIM, row_start, s_srt, t_srt, w_srt, stats);
    gemm_mfma_k<<<(NNODES + 127) / 128, 512, 0, stream>>>(
        stats, scales, xbuf, wtbuf + (size_t)l * NCHUNK * 2 * 128 * APAD, Ybuf);
    ln_k<<<(NNODES + 3) / 4, 256, 0, stream>>>(
        Ybuf, lin_b + (size_t)l * DIM, ln_g + (size_t)l * DIM, lnb + (size_t)l * DIM, xbuf);
  }
  score_k<<<(NTRIPLES + 3) / 4, 256, 0, stream>>>(xbuf, qw, srcq, relq, dstq, out);
}